// Round 1
// baseline (744.803 us; speedup 1.0000x reference)
//
#include <hip/hip_runtime.h>
#include <cstddef>

#define LOG2PI_F 1.8378770664093453f

__device__ __forceinline__ float wave_sum(float v) {
#pragma unroll
    for (int o = 32; o >= 1; o >>= 1) v += __shfl_xor(v, o, 64);
    return v;
}

// ---------------------------------------------------------------------------
// logrb[g] = log(rho_bias[g])
__global__ void k_logrb(const float* __restrict__ rho_bias, float* __restrict__ logrb, int G_total) {
    int g = blockIdx.x * blockDim.x + threadIdx.x;
    if (g < G_total) logrb[g] = __logf(rho_bias[g]);
}

// ---------------------------------------------------------------------------
// Per selected gene: copy heights row, softmax widths, bin locations.
// 1 wave per gene.
__global__ void k_prep_genes(const int* __restrict__ genes_oi,
                             const float* __restrict__ uh, const float* __restrict__ uw,
                             float* __restrict__ uh_sel, float* __restrict__ w_ws,
                             float* __restrict__ loc_ws) {
    const int g = blockIdx.x;
    const int t = threadIdx.x;
    const int gs = genes_oi[g];

    for (int c = t; c < 224; c += 64) uh_sel[(size_t)g * 224 + c] = uh[(size_t)gs * 224 + c];

    __shared__ float w_s[128];
    int oh = 0, ow = 0;
    const int NH[3] = {128, 64, 32};
    for (int lev = 0; lev < 3; ++lev) {
        const int nh = NH[lev], nw = nh - 1;
        float v0 = (t < nw)      ? uw[(size_t)gs * 221 + ow + t]      : -INFINITY;
        float v1 = (t + 64 < nw) ? uw[(size_t)gs * 221 + ow + t + 64] : -INFINITY;
        float mx = fmaxf(v0, v1);
#pragma unroll
        for (int o = 32; o >= 1; o >>= 1) mx = fmaxf(mx, __shfl_xor(mx, o, 64));
        float e0 = (t < nw)      ? __expf(v0 - mx) : 0.f;
        float e1 = (t + 64 < nw) ? __expf(v1 - mx) : 0.f;
        float sm = wave_sum(e0 + e1);
        float inv = 1.0f / sm;
        float w0 = e0 * inv, w1 = e1 * inv;
        if (t < nw)      { w_s[t]      = w0; w_ws[(size_t)g * 221 + ow + t]      = w0; }
        if (t + 64 < nw) { w_s[t + 64] = w1; w_ws[(size_t)g * 221 + ow + t + 64] = w1; }
        __syncthreads();
        // loc[k] = sum_{j<k} w[j], loc[nh-1] = 1  (serial per lane; tiny)
        for (int k = t; k < nh; k += 64) {
            float acc = 0.f;
            for (int j = 0; j < k; ++j) acc += w_s[j];
            loc_ws[(size_t)g * 224 + oh + k] = (k == nh - 1) ? 1.0f : acc;
        }
        __syncthreads();
        oh += nh; ow += nw;
    }
}

// ---------------------------------------------------------------------------
// Transpose lw_oi to (g, c, l) layout; fused prior ssq for lw row + rw row.
__global__ void k_prep_lwT(const int* __restrict__ genes_oi,
                           const float* __restrict__ lw, const float* __restrict__ rw,
                           float* __restrict__ lwT, float* __restrict__ pB) {
    const int g = blockIdx.x;
    const int tid = threadIdx.x;
    const int gs = genes_oi[g];
    const float* src = lw + (size_t)gs * 3584;
    float* dst = lwT + (size_t)g * 3584;
    float acc = 0.f;
    if (tid < 224) {
        float vv[16];
#pragma unroll
        for (int l = 0; l < 16; ++l) {
            float v = src[l * 224 + tid];
            vv[l] = v;
            acc = fmaf(v, v, acc);
        }
        float4* d4 = (float4*)(dst + (size_t)tid * 16);
#pragma unroll
        for (int q = 0; q < 4; ++q)
            d4[q] = make_float4(vv[4 * q + 0], vv[4 * q + 1], vv[4 * q + 2], vv[4 * q + 3]);
    }
    if (tid < 16) { float v = rw[(size_t)gs * 16 + tid]; acc = fmaf(v, v, acc); }
    __shared__ float sm[256];
    sm[tid] = acc;
    __syncthreads();
    for (int o = 128; o > 0; o >>= 1) { if (tid < o) sm[tid] += sm[tid + o]; __syncthreads(); }
    if (tid == 0) pB[g] = 0.5f * sm[0] + 0.5f * LOG2PI_F * (3584.0f + 16.0f);
}

// ---------------------------------------------------------------------------
// Per-cell log-sum-exp over all G_total genes of (log rho_bias + cl·rw).
__global__ void k_lse(const float* __restrict__ clustering, const float* __restrict__ rw,
                      const float* __restrict__ logrb, float* __restrict__ lse, int G_total) {
    const int b = blockIdx.x;
    const int tid = threadIdx.x;
    __shared__ float cl_s[16];
    if (tid < 16) cl_s[tid] = clustering[(size_t)b * 16 + tid];
    __syncthreads();
    float m = -INFINITY, s = 0.f;
    for (int g = tid; g < G_total; g += blockDim.x) {
        const float4* r4 = (const float4*)(rw + (size_t)g * 16);
        float d = 0.f;
#pragma unroll
        for (int q = 0; q < 4; ++q) {
            float4 v = r4[q];
            d = fmaf(cl_s[4 * q + 0], v.x, d);
            d = fmaf(cl_s[4 * q + 1], v.y, d);
            d = fmaf(cl_s[4 * q + 2], v.z, d);
            d = fmaf(cl_s[4 * q + 3], v.w, d);
        }
        float logit = logrb[g] + d;
        float mn = fmaxf(m, logit);
        s = s * __expf(m - mn) + __expf(logit - mn);
        m = mn;
    }
    __shared__ float ms[256], ss[256];
    ms[tid] = m; ss[tid] = s;
    __syncthreads();
    for (int o = 128; o > 0; o >>= 1) {
        if (tid < o) {
            float m2 = ms[tid + o], s2 = ss[tid + o];
            float mn = fmaxf(ms[tid], m2);
            ss[tid] = ss[tid] * __expf(ms[tid] - mn) + s2 * __expf(m2 - mn);
            ms[tid] = mn;
        }
        __syncthreads();
    }
    if (tid == 0) lse[b] = ms[0] + __logf(ss[0]);
}

// ---------------------------------------------------------------------------
// Main: one wave per cut, grid-stride. 3-level quadratic spline + lik_overall.
__launch_bounds__(256)
__global__ void k_main(const float* __restrict__ coordinates,
                       const int* __restrict__ local_gene_ix,
                       const int* __restrict__ local_cellxgene_ix,
                       const int* __restrict__ localcellxgene_ix,
                       const float* __restrict__ clustering,
                       const float* __restrict__ lwT,
                       const float* __restrict__ rw,
                       const float* __restrict__ logrb,
                       const float* __restrict__ lse,
                       const float* __restrict__ uh_sel,
                       const float* __restrict__ w_ws,
                       const float* __restrict__ loc_ws,
                       float* __restrict__ pA,
                       int N, int G_oi, int G_total) {
    const int tid  = threadIdx.x;
    const int lane = tid & 63;
    const int wid  = tid >> 6;
    const int wglobal = blockIdx.x * 4 + wid;
    const int wstride = gridDim.x * 4;
    const float logGt = __logf((float)G_total);

    float acc = 0.f;

    for (int i = wglobal; i < N; i += wstride) {
        const float x_in = coordinates[i];
        const int g_h = local_gene_ix[i];
        const int lcx = local_cellxgene_ix[i];
        const int lc2 = localcellxgene_ix[i];
        const unsigned b1 = (unsigned)lcx / (unsigned)G_oi;
        const unsigned gm = (unsigned)lcx - b1 * (unsigned)G_oi;
        const unsigned b2 = (unsigned)lc2 / (unsigned)G_total;
        const unsigned gt = (unsigned)lc2 - b2 * (unsigned)G_total;

        float cl[16];
        {
            const float4* c4 = (const float4*)(clustering + (size_t)b1 * 16);
#pragma unroll
            for (int q = 0; q < 4; ++q) {
                float4 v = c4[q];
                cl[4 * q + 0] = v.x; cl[4 * q + 1] = v.y; cl[4 * q + 2] = v.z; cl[4 * q + 3] = v.w;
            }
        }

        const float* lwtg = lwT   + (size_t)gm  * 3584;
        const float* uhg  = uh_sel + (size_t)g_h * 224;
        const float* wg   = w_ws   + (size_t)g_h * 221;
        const float* lg   = loc_ws + (size_t)g_h * 224;

        float x = x_in;
        float lad = 0.f;
        int oh = 0, ow = 0;
        const int NH[3] = {128, 64, 32};
#pragma unroll
        for (int lev = 0; lev < 3; ++lev) {
            const int n = NH[lev];
            const int c0 = lane, c1 = lane + 64;
            const bool a0 = (c0 < n);
            const bool a1 = (n > 64);
            float h0 = 0.f, h1 = 0.f;
            if (a0) {
                const float4* p4 = (const float4*)(lwtg + (size_t)(oh + c0) * 16);
                float d = 0.f;
#pragma unroll
                for (int q = 0; q < 4; ++q) {
                    float4 v = p4[q];
                    d = fmaf(cl[4 * q + 0], v.x, d);
                    d = fmaf(cl[4 * q + 1], v.y, d);
                    d = fmaf(cl[4 * q + 2], v.z, d);
                    d = fmaf(cl[4 * q + 3], v.w, d);
                }
                h0 = __expf(uhg[oh + c0] + d);
            }
            if (a1) {
                const float4* p4 = (const float4*)(lwtg + (size_t)(oh + c1) * 16);
                float d = 0.f;
#pragma unroll
                for (int q = 0; q < 4; ++q) {
                    float4 v = p4[q];
                    d = fmaf(cl[4 * q + 0], v.x, d);
                    d = fmaf(cl[4 * q + 1], v.y, d);
                    d = fmaf(cl[4 * q + 2], v.z, d);
                    d = fmaf(cl[4 * q + 3], v.w, d);
                }
                h1 = __expf(uhg[oh + c1] + d);
            }
            const float h0n = __shfl(h0, (lane + 1) & 63, 64);
            const float h1n = __shfl(h1, (lane + 1) & 63, 64);
            const float h64 = __shfl(h1, 0, 64);

            float segA = 0.f, segB = 0.f;
            if (lane < n - 1) {
                float hr = (lane < 63) ? h0n : h64;   // lane==63 only when n==128
                segA = 0.5f * (h0 + hr) * wg[ow + lane];
            }
            if (a1 && lane < 63) {                    // j = lane+64 <= 126
                segB = 0.5f * (h1 + h1n) * wg[ow + lane + 64];
            }

            float loc0 = a0 ? lg[oh + c0] : 2.f;
            float loc1 = a1 ? lg[oh + c1] : 2.f;
            unsigned long long bb0 = __ballot(a0 && (x >= loc0));
            unsigned long long bb1 = __ballot(a1 && (x >= loc1));
            int cnt = __popcll(bb0) + __popcll(bb1);
            int bi = min(max(cnt - 1, 0), n - 2);

            float pref = ((lane < bi) ? segA : 0.f) + (((lane + 64) < bi) ? segB : 0.f);
            float area = wave_sum(segA + segB);
            float cdf_raw = wave_sum(pref);

            float hl  = (bi < 64)     ? __shfl(h0, bi, 64)     : __shfl(h1, bi - 64, 64);
            int bip = bi + 1;
            float hr2 = (bip < 64)    ? __shfl(h0, bip, 64)    : __shfl(h1, bip - 64, 64);

            float inv_area = 1.0f / area;
            float loc_l = lg[oh + bi];
            float w_b   = wg[ow + bi];
            float hlr = hl * inv_area, hrr = hr2 * inv_area;
            float alpha = (x - loc_l) / w_b;
            x = 0.5f * (hrr - hlr) * w_b * alpha * alpha + hlr * w_b * alpha + cdf_raw * inv_area;
            lad += __logf(hlr + (hrr - hlr) * alpha);
            oh += n; ow += n - 1;
        }

        // lik_overall = logrb[gt] + cl[b2]·rw[gt] - lse[b2] + log(G_total)
        float d2 = 0.f;
        {
            const float4* c4 = (const float4*)(clustering + (size_t)b2 * 16);
            const float4* r4 = (const float4*)(rw + (size_t)gt * 16);
#pragma unroll
            for (int q = 0; q < 4; ++q) {
                float4 cv = c4[q], rv = r4[q];
                d2 = fmaf(cv.x, rv.x, d2);
                d2 = fmaf(cv.y, rv.y, d2);
                d2 = fmaf(cv.z, rv.z, d2);
                d2 = fmaf(cv.w, rv.w, d2);
            }
        }
        float lik_ov = logrb[gt] + d2 - lse[b2] + logGt;
        acc += -(lad + lik_ov);
    }

    __shared__ float wsum[4];
    if (lane == 0) wsum[wid] = acc;
    __syncthreads();
    if (tid == 0) pA[blockIdx.x] = wsum[0] + wsum[1] + wsum[2] + wsum[3];
}

// ---------------------------------------------------------------------------
__global__ void k_final(const float* __restrict__ pA, const float* __restrict__ pB,
                        float* __restrict__ out, int nA, int nB) {
    const int tid = threadIdx.x;
    float acc = 0.f;
    for (int i = tid; i < nA; i += blockDim.x) acc += pA[i];
    for (int i = tid; i < nB; i += blockDim.x) acc += pB[i];
    __shared__ float sm[256];
    sm[tid] = acc;
    __syncthreads();
    for (int o = 128; o > 0; o >>= 1) { if (tid < o) sm[tid] += sm[tid + o]; __syncthreads(); }
    if (tid == 0) out[0] = sm[0];
}

// ---------------------------------------------------------------------------
extern "C" void kernel_launch(void* const* d_in, const int* in_sizes, int n_in,
                              void* d_out, int out_size, void* d_ws, size_t ws_size,
                              hipStream_t stream) {
    const float* clustering        = (const float*)d_in[0];
    const float* coordinates       = (const float*)d_in[1];
    const int*   genes_oi          = (const int*)d_in[2];
    const int*   local_gene_ix     = (const int*)d_in[3];
    const int*   local_cellxgene_ix= (const int*)d_in[4];
    const int*   localcellxgene_ix = (const int*)d_in[5];
    const float* lw                = (const float*)d_in[6];
    const float* rw                = (const float*)d_in[7];
    const float* rho_bias          = (const float*)d_in[8];
    const float* uh                = (const float*)d_in[9];
    const float* uw                = (const float*)d_in[10];

    const int G_total = in_sizes[8];                  // 20000
    const int G_oi    = in_sizes[2];                  // 500
    const int N       = in_sizes[1];                  // 200000
    const int L       = in_sizes[7] / G_total;        // 16
    const int B       = in_sizes[0] / L;              // 512
    (void)L;

    const int NBLK = 2048;

    size_t off = 0;
    float* base = (float*)d_ws;
    auto alloc = [&](size_t nfloats) {
        float* p = base + off;
        off += (nfloats + 3) & ~(size_t)3;   // 16 B alignment
        return p;
    };
    float* pA      = alloc(NBLK);
    float* pB      = alloc(G_oi);
    float* lse     = alloc(B);
    float* logrb   = alloc(G_total);
    float* lwT     = alloc((size_t)G_oi * 3584);
    float* uh_sel  = alloc((size_t)G_oi * 224);
    float* w_ws    = alloc((size_t)G_oi * 221);
    float* loc_ws  = alloc((size_t)G_oi * 224);
    (void)ws_size;

    k_logrb<<<(G_total + 255) / 256, 256, 0, stream>>>(rho_bias, logrb, G_total);
    k_prep_genes<<<G_oi, 64, 0, stream>>>(genes_oi, uh, uw, uh_sel, w_ws, loc_ws);
    k_prep_lwT<<<G_oi, 256, 0, stream>>>(genes_oi, lw, rw, lwT, pB);
    k_lse<<<B, 256, 0, stream>>>(clustering, rw, logrb, lse, G_total);
    k_main<<<NBLK, 256, 0, stream>>>(coordinates, local_gene_ix, local_cellxgene_ix,
                                     localcellxgene_ix, clustering, lwT, rw, logrb, lse,
                                     uh_sel, w_ws, loc_ws, pA, N, G_oi, G_total);
    k_final<<<1, 256, 0, stream>>>(pA, pB, (float*)d_out, NBLK, G_oi);
}

// Round 2
// 674.782 us; speedup vs baseline: 1.1038x; 1.1038x over previous
//
#include <hip/hip_runtime.h>
#include <cstddef>

#define LOG2PI_F 1.8378770664093453f

__device__ __forceinline__ float wave_sum(float v) {
#pragma unroll
    for (int o = 32; o >= 1; o >>= 1) v += __shfl_xor(v, o, 64);
    return v;
}
__device__ __forceinline__ float wave_max(float v) {
#pragma unroll
    for (int o = 32; o >= 1; o >>= 1) v = fmaxf(v, __shfl_xor(v, o, 64));
    return v;
}
__device__ __forceinline__ float wave_scan_incl(float v, int lane) {
#pragma unroll
    for (int o = 1; o < 64; o <<= 1) {
        float t = __shfl_up(v, o, 64);
        if (lane >= o) v += t;
    }
    return v;
}

// ---------------------------------------------------------------------------
__global__ void k_logrb(const float* __restrict__ rho_bias, float* __restrict__ logrb, int G_total) {
    int g = blockIdx.x * blockDim.x + threadIdx.x;
    if (g < G_total) logrb[g] = __logf(rho_bias[g]);
}

// ---------------------------------------------------------------------------
// Per selected gene: softmax widths, bin locations, packed per-step table.
// pk[g][j] for step j of each level: (uh[oh+j+1], 0.5*w[j], loc[j+1], 0)
// pk[g][127] = (uh[0], uh[128], uh[192], 0)   -- level-start heights
// 1 wave per gene.
__global__ void k_prep_genes(const int* __restrict__ genes_oi,
                             const float* __restrict__ uh, const float* __restrict__ uw,
                             float4* __restrict__ pk) {
    const int g = blockIdx.x;
    const int t = threadIdx.x;
    const int gs = genes_oi[g];
    const float* uhg = uh + (size_t)gs * 224;
    const float* uwg = uw + (size_t)gs * 221;
    float4* pkg = pk + (size_t)g * 224;

    const int NH[3] = {128, 64, 32};
    const int OH[3] = {0, 128, 192};
    const int OW[3] = {0, 127, 190};
    const int SO[3] = {0, 128, 191};
#pragma unroll
    for (int lev = 0; lev < 3; ++lev) {
        const int nw = NH[lev] - 1;
        float v0 = (t < nw)      ? uwg[OW[lev] + t]      : -INFINITY;
        float v1 = (t + 64 < nw) ? uwg[OW[lev] + t + 64] : -INFINITY;
        float mx = wave_max(fmaxf(v0, v1));
        float e0 = (t < nw)      ? __expf(v0 - mx) : 0.f;
        float e1 = (t + 64 < nw) ? __expf(v1 - mx) : 0.f;
        float inv = 1.0f / wave_sum(e0 + e1);
        float w0 = e0 * inv, w1 = e1 * inv;
        float i0 = wave_scan_incl(w0, t);
        float tot0 = __shfl(i0, 63, 64);
        float i1 = wave_scan_incl(w1, t) + tot0;
        if (t < nw) {
            float loc = (t == nw - 1) ? 1.0f : i0;
            pkg[SO[lev] + t] = make_float4(uhg[OH[lev] + t + 1], 0.5f * w0, loc, 0.f);
        }
        if (t + 64 < nw) {
            int j = t + 64;
            float loc = (j == nw - 1) ? 1.0f : i1;
            pkg[SO[lev] + j] = make_float4(uhg[OH[lev] + j + 1], 0.5f * w1, loc, 0.f);
        }
    }
    if (t == 0) pkg[127] = make_float4(uhg[0], uhg[128], uhg[192], 0.f);
}

// ---------------------------------------------------------------------------
// Transpose lw_oi to (g, c, l) row-major; fused prior ssq for lw row + rw row.
__global__ void k_prep_lwT(const int* __restrict__ genes_oi,
                           const float* __restrict__ lw, const float* __restrict__ rw,
                           float* __restrict__ lwT, float* __restrict__ pB) {
    const int g = blockIdx.x;
    const int tid = threadIdx.x;
    const int gs = genes_oi[g];
    const float* src = lw + (size_t)gs * 3584;
    float* dst = lwT + (size_t)g * 3584;
    float acc = 0.f;
    if (tid < 224) {
        float vv[16];
#pragma unroll
        for (int l = 0; l < 16; ++l) {
            float v = src[l * 224 + tid];
            vv[l] = v;
            acc = fmaf(v, v, acc);
        }
        float4* d4 = (float4*)(dst + (size_t)tid * 16);
#pragma unroll
        for (int q = 0; q < 4; ++q)
            d4[q] = make_float4(vv[4 * q + 0], vv[4 * q + 1], vv[4 * q + 2], vv[4 * q + 3]);
    }
    if (tid < 16) { float v = rw[(size_t)gs * 16 + tid]; acc = fmaf(v, v, acc); }
    __shared__ float sm[256];
    sm[tid] = acc;
    __syncthreads();
    for (int o = 128; o > 0; o >>= 1) { if (tid < o) sm[tid] += sm[tid + o]; __syncthreads(); }
    if (tid == 0) pB[g] = 0.5f * sm[0] + 0.5f * LOG2PI_F * (3584.0f + 16.0f);
}

// ---------------------------------------------------------------------------
// Per-cell log-sum-exp over all G_total genes of (log rho_bias + cl·rw).
__global__ void k_lse(const float* __restrict__ clustering, const float* __restrict__ rw,
                      const float* __restrict__ logrb, float* __restrict__ lse, int G_total) {
    const int b = blockIdx.x;
    const int tid = threadIdx.x;
    __shared__ float cl_s[16];
    if (tid < 16) cl_s[tid] = clustering[(size_t)b * 16 + tid];
    __syncthreads();
    float m = -INFINITY, s = 0.f;
    for (int g = tid; g < G_total; g += blockDim.x) {
        const float4* r4 = (const float4*)(rw + (size_t)g * 16);
        float d = 0.f;
#pragma unroll
        for (int q = 0; q < 4; ++q) {
            float4 v = r4[q];
            d = fmaf(cl_s[4 * q + 0], v.x, d);
            d = fmaf(cl_s[4 * q + 1], v.y, d);
            d = fmaf(cl_s[4 * q + 2], v.z, d);
            d = fmaf(cl_s[4 * q + 3], v.w, d);
        }
        float logit = logrb[g] + d;
        float mn = fmaxf(m, logit);
        s = s * __expf(m - mn) + __expf(logit - mn);
        m = mn;
    }
    __shared__ float ms[256], ss[256];
    ms[tid] = m; ss[tid] = s;
    __syncthreads();
    for (int o = 128; o > 0; o >>= 1) {
        if (tid < o) {
            float m2 = ms[tid + o], s2 = ss[tid + o];
            float mn = fmaxf(ms[tid], m2);
            ss[tid] = ss[tid] * __expf(ms[tid] - mn) + s2 * __expf(m2 - mn);
            ms[tid] = mn;
        }
        __syncthreads();
    }
    if (tid == 0) lse[b] = ms[0] + __logf(ss[0]);
}

// ---------------------------------------------------------------------------
// Bucketing: histogram over gm = lcx % G_oi, scan, scatter.
__global__ void k_zero(int* __restrict__ p, int n) {
    int i = blockIdx.x * blockDim.x + threadIdx.x;
    if (i < n) p[i] = 0;
}

__global__ void k_hist(const int* __restrict__ lcx, int* __restrict__ counts, int N, int G_oi) {
    int i = blockIdx.x * blockDim.x + threadIdx.x;
    if (i < N) atomicAdd(&counts[(unsigned)lcx[i] % (unsigned)G_oi], 1);
}

__global__ void k_scan(const int* __restrict__ counts, int* __restrict__ offsets,
                       int* __restrict__ cursor, int G_oi) {
    __shared__ int sm[512];
    const int t = threadIdx.x;
    int v = (t < G_oi) ? counts[t] : 0;
    sm[t] = v;
    __syncthreads();
    for (int o = 1; o < 512; o <<= 1) {
        int add = (t >= o) ? sm[t - o] : 0;
        __syncthreads();
        sm[t] += add;
        __syncthreads();
    }
    if (t < G_oi) {
        offsets[t + 1] = sm[t];
        cursor[t] = sm[t] - v;
    }
    if (t == 0) offsets[0] = 0;
}

__global__ void k_scatter(const float* __restrict__ coord, const int* __restrict__ lgix,
                          const int* __restrict__ lcx, const int* __restrict__ lc2,
                          int* __restrict__ cursor,
                          float* __restrict__ xs, int* __restrict__ b1s,
                          int* __restrict__ lc2s, int* __restrict__ ghs, int N, int G_oi) {
    int i = blockIdx.x * blockDim.x + threadIdx.x;
    if (i >= N) return;
    unsigned v = (unsigned)lcx[i];
    unsigned g = v % (unsigned)G_oi;
    int pos = atomicAdd(&cursor[g], 1);
    xs[pos]   = coord[i];
    b1s[pos]  = (int)(v / (unsigned)G_oi);
    lc2s[pos] = lc2[i];
    ghs[pos]  = lgix[i];
}

// ---------------------------------------------------------------------------
// Main: one block per gene (gm bucket), one thread per cut. lwT rows are
// block-uniform (scalar loads); per-cut tables via one float4 gather/step.
__launch_bounds__(512, 4)
__global__ void k_main2(const float* __restrict__ xs, const int* __restrict__ b1s,
                        const int* __restrict__ lc2s, const int* __restrict__ ghs,
                        const int* __restrict__ offsets,
                        const float* __restrict__ clustering,
                        const float* __restrict__ lwT,    // [g][224][16]
                        const float4* __restrict__ pk,    // [g_h][224]
                        const float* __restrict__ rw,
                        const float* __restrict__ logrb,
                        const float* __restrict__ lse,
                        float* __restrict__ pA, int G_oi, int G_total) {
    const int g = blockIdx.x;
    const int tid = threadIdx.x;
    const float* lwg = lwT + (size_t)g * 3584;
    const int s = offsets[g], e = offsets[g + 1];
    const float logGt = __logf((float)G_total);
    float acc = 0.f;

    for (int base = s; base < e; base += 512) {
        const int i = base + tid;
        const bool valid = i < e;
        const int isafe = valid ? i : s;
        float x = xs[isafe];
        const int b1  = b1s[isafe];
        const int lc2 = lc2s[isafe];
        const int gh  = ghs[isafe];
        const float4* pkh = pk + (size_t)gh * 224;

        float cl[16];
        {
            const float4* c4 = (const float4*)(clustering + (size_t)b1 * 16);
#pragma unroll
            for (int q = 0; q < 4; ++q) {
                float4 v = c4[q];
                cl[4 * q + 0] = v.x; cl[4 * q + 1] = v.y; cl[4 * q + 2] = v.z; cl[4 * q + 3] = v.w;
            }
        }
        const float4 uh0 = pkh[127];
        const float uh0v[3] = {uh0.x, uh0.y, uh0.z};

        float lad = 0.f;
        const int NH[3] = {128, 64, 32};
        const int OH[3] = {0, 128, 192};
        const int SO[3] = {0, 128, 191};
#pragma unroll
        for (int lev = 0; lev < 3; ++lev) {
            const int nw = NH[lev] - 1;
            const float* rowbase = lwg + (size_t)OH[lev] * 16;
            float hp;
            {
                float d = 0.f;
#pragma unroll
                for (int l = 0; l < 16; ++l) d = fmaf(cl[l], rowbase[l], d);
                hp = __expf(uh0v[lev] + d);
            }
            float h_l = hp, h_r = hp, whb = 0.f, loc_l = 0.f, cdf = 0.f, area = 0.f;
            int in = 0;
            const float4* pks = pkh + SO[lev];
            for (int j = 0; j < nw; ++j) {
                const float* row = rowbase + (size_t)(j + 1) * 16;
                float d = 0.f;
#pragma unroll
                for (int l = 0; l < 16; ++l) d = fmaf(cl[l], row[l], d);
                float4 pkv = pks[j];
                float hn = __expf(pkv.x + d);
                float seg = (hp + hn) * pkv.y;
                bool inJ = (in == j);
                if (inJ) { h_r = hn; whb = pkv.y; }
                bool adv = (x >= pkv.z) && (j < nw - 1);
                if (adv) { cdf += seg; h_l = hn; loc_l = pkv.z; in = j + 1; }
                area += seg;
                hp = hn;
            }
            float inv_area = __builtin_amdgcn_rcpf(area);
            float alpha = (x - loc_l) * 0.5f * __builtin_amdgcn_rcpf(whb);
            float t2 = whb * alpha;
            x = (t2 * fmaf(h_r - h_l, alpha, 2.f * h_l) + cdf) * inv_area;
            lad += __logf(fmaf(h_r - h_l, alpha, h_l)) - __logf(area);
        }

        // lik_overall = logrb[gt] + cl[b2]·rw[gt] - lse[b2] + log(G_total)
        unsigned b2 = (unsigned)lc2 / (unsigned)G_total;
        unsigned gt = (unsigned)lc2 - b2 * (unsigned)G_total;
        float d2 = 0.f;
        {
            const float4* c24 = (const float4*)(clustering + (size_t)b2 * 16);
            const float4* r4  = (const float4*)(rw + (size_t)gt * 16);
#pragma unroll
            for (int q = 0; q < 4; ++q) {
                float4 a = c24[q], b = r4[q];
                d2 = fmaf(a.x, b.x, d2); d2 = fmaf(a.y, b.y, d2);
                d2 = fmaf(a.z, b.z, d2); d2 = fmaf(a.w, b.w, d2);
            }
        }
        float lik = logrb[gt] + d2 - lse[b2] + logGt;
        if (valid) acc -= (lad + lik);
    }

    acc = wave_sum(acc);
    __shared__ float wsm[8];
    if ((tid & 63) == 0) wsm[tid >> 6] = acc;
    __syncthreads();
    if (tid == 0) {
        float t = 0.f;
#pragma unroll
        for (int w = 0; w < 8; ++w) t += wsm[w];
        pA[g] = t;
    }
}

// ---------------------------------------------------------------------------
__global__ void k_final(const float* __restrict__ pA, const float* __restrict__ pB,
                        float* __restrict__ out, int nA, int nB) {
    const int tid = threadIdx.x;
    float acc = 0.f;
    for (int i = tid; i < nA; i += blockDim.x) acc += pA[i];
    for (int i = tid; i < nB; i += blockDim.x) acc += pB[i];
    __shared__ float sm[256];
    sm[tid] = acc;
    __syncthreads();
    for (int o = 128; o > 0; o >>= 1) { if (tid < o) sm[tid] += sm[tid + o]; __syncthreads(); }
    if (tid == 0) out[0] = sm[0];
}

// ---------------------------------------------------------------------------
extern "C" void kernel_launch(void* const* d_in, const int* in_sizes, int n_in,
                              void* d_out, int out_size, void* d_ws, size_t ws_size,
                              hipStream_t stream) {
    const float* clustering        = (const float*)d_in[0];
    const float* coordinates       = (const float*)d_in[1];
    const int*   genes_oi          = (const int*)d_in[2];
    const int*   local_gene_ix     = (const int*)d_in[3];
    const int*   local_cellxgene_ix= (const int*)d_in[4];
    const int*   localcellxgene_ix = (const int*)d_in[5];
    const float* lw                = (const float*)d_in[6];
    const float* rw                = (const float*)d_in[7];
    const float* rho_bias          = (const float*)d_in[8];
    const float* uh                = (const float*)d_in[9];
    const float* uw                = (const float*)d_in[10];

    const int G_total = in_sizes[8];                  // 20000
    const int G_oi    = in_sizes[2];                  // 500
    const int N       = in_sizes[1];                  // 200000
    const int L       = in_sizes[7] / G_total;        // 16
    const int B       = in_sizes[0] / L;              // 512

    size_t off = 0;
    char* base = (char*)d_ws;
    auto alloc = [&](size_t nbytes) {
        char* p = base + off;
        off = (off + nbytes + 15) & ~(size_t)15;
        return (void*)p;
    };
    float*  pA      = (float*)alloc(sizeof(float) * (G_oi + 16));
    float*  pB      = (float*)alloc(sizeof(float) * (G_oi + 16));
    float*  lse     = (float*)alloc(sizeof(float) * (B + 16));
    float*  logrb   = (float*)alloc(sizeof(float) * G_total);
    float*  lwT     = (float*)alloc(sizeof(float) * (size_t)G_oi * 3584);
    float4* pk      = (float4*)alloc(sizeof(float4) * (size_t)G_oi * 224);
    int*    counts  = (int*)alloc(sizeof(int) * 512);
    int*    offsets = (int*)alloc(sizeof(int) * 512);
    int*    cursor  = (int*)alloc(sizeof(int) * 512);
    float*  xs      = (float*)alloc(sizeof(float) * N);
    int*    b1s     = (int*)alloc(sizeof(int) * N);
    int*    lc2s    = (int*)alloc(sizeof(int) * N);
    int*    ghs     = (int*)alloc(sizeof(int) * N);
    (void)ws_size;

    const int TPB = 256;
    k_logrb<<<(G_total + TPB - 1) / TPB, TPB, 0, stream>>>(rho_bias, logrb, G_total);
    k_prep_genes<<<G_oi, 64, 0, stream>>>(genes_oi, uh, uw, pk);
    k_prep_lwT<<<G_oi, 256, 0, stream>>>(genes_oi, lw, rw, lwT, pB);
    k_lse<<<B, 256, 0, stream>>>(clustering, rw, logrb, lse, G_total);
    k_zero<<<2, 256, 0, stream>>>(counts, 512);
    k_hist<<<(N + TPB - 1) / TPB, TPB, 0, stream>>>(local_cellxgene_ix, counts, N, G_oi);
    k_scan<<<1, 512, 0, stream>>>(counts, offsets, cursor, G_oi);
    k_scatter<<<(N + TPB - 1) / TPB, TPB, 0, stream>>>(coordinates, local_gene_ix,
                                                       local_cellxgene_ix, localcellxgene_ix,
                                                       cursor, xs, b1s, lc2s, ghs, N, G_oi);
    k_main2<<<G_oi, 512, 0, stream>>>(xs, b1s, lc2s, ghs, offsets, clustering, lwT, pk,
                                      rw, logrb, lse, pA, G_oi, G_total);
    k_final<<<1, 256, 0, stream>>>(pA, pB, (float*)d_out, G_oi, G_oi);
}